// Round 19
// baseline (352.724 us; speedup 1.0000x reference)
//
#include <hip/hip_runtime.h>
#include <stdint.h>

typedef __attribute__((ext_vector_type(8))) short short8v;
typedef __attribute__((ext_vector_type(4))) float f32x4;

#define ATTN_NORM 0.13363062095621219f
#define LOG2E 1.4426950408889634f

// exact RNE (used only in W-prep, off the hot path)
__device__ __forceinline__ unsigned short f2bf(float f) {
  union { float f; uint32_t u; } v; v.f = f;
  uint32_t u = v.u;
  u += 0x7fffu + ((u >> 16) & 1u);
  return (unsigned short)(u >> 16);
}

// fast round-half-up scalar (2 VALU)
__device__ __forceinline__ unsigned short f2bf_fast(float f) {
  union { float f; uint32_t u; } v; v.f = f;
  return (unsigned short)((v.u + 0x8000u) >> 16);
}

// fast packed pair: 2 adds + 1 v_perm_b32 (builtin — asm cvt_pk is banned: R3/R8/R9 NaN)
__device__ __forceinline__ uint32_t pack2bf(float lo, float hi) {
  union { float f; uint32_t u; } a, b;
  a.f = lo; b.f = hi;
  return __builtin_amdgcn_perm(b.u + 0x8000u, a.u + 0x8000u, 0x07060302u);
}

// ============ fused prep(W) + conv(x) kernel (proven R14) ============
template<int W, int D, int XO, int BLK0, int NB>
__device__ __forceinline__ void conv_pass(const float* __restrict__ xp,
                                          unsigned short* __restrict__ xo,
                                          unsigned short* __restrict__ lds, int tid) {
  constexpr int PITCH = W + 8;
  #pragma unroll 2
  for (int f = tid; f < 64 * (W / 4); f += 256) {
    int tok = f / (W / 4);
    int c4 = f - tok * (W / 4);
    float4 v = *(const float4*)(xp + tok * 960 + XO + c4 * 4);
    uint2 pk = make_uint2(pack2bf(v.x, v.y), pack2bf(v.z, v.w));
    *(uint2*)(lds + tok * PITCH + c4 * 4) = pk;
  }
  __syncthreads();
  #pragma unroll 2
  for (int f = tid; f < NB * 64; f += 256) {
    int bl = f >> 6, lane = f & 63;
    int mb, i, qt;
    if (D == 1) {
      int c2 = bl >> 4, t = bl & 15;
      mb = c2 * 128 + (t >> 2) * 32; i = 0; qt = t & 3;
    } else if (D == 3) {
      int c2 = bl / 24; int t = bl - c2 * 24;
      int ks = t / 12; int rt = t - ks * 12;
      mb = c2 * 64 + ks * 32; i = rt >> 2; qt = rt & 3;
    } else {
      int c2 = bl / 20; int rt = bl - c2 * 20;
      mb = c2 * 32; i = rt >> 2; qt = rt & 3;
    }
    int tok = qt * 16 + (lane & 15);
    int m0 = mb + (lane >> 4) * 8;
    const unsigned short* base = lds + tok * PITCH + m0 * D + i;
    union { unsigned short o[8]; short8v s; } pk;
    #pragma unroll
    for (int e = 0; e < 8; ++e) pk.o[e] = base[e * D];
    *(short8v*)(xo + (BLK0 + bl) * 512 + lane * 8) = pk.s;
  }
}

__launch_bounds__(256)
__global__ void prep_conv(const float* __restrict__ x,
                          const float* q0, const float* q1, const float* q2,
                          const float* k0, const float* k1, const float* k2,
                          const float* v0, const float* v1, const float* v2,
                          unsigned short* __restrict__ ws,
                          unsigned short* __restrict__ xw) {
  __shared__ unsigned short lds[25088];
  int bid = blockIdx.x, tid = threadIdx.x;
  if (bid < 3072) {
    int b, pass;
    if (bid < 1024)       { b = bid;        pass = 0; }
    else if (bid < 2048)  { b = bid - 1024; pass = 1; }
    else                  { b = bid - 2048; pass = 2; }
    const float* xp = x + (size_t)b * 61440;
    unsigned short* xo = xw + (size_t)b * 61440;
    if (pass == 0)      conv_pass<256, 1,   0,  0, 32>(xp, xo, lds, tid);
    else if (pass == 1) conv_pass<384, 3, 256, 32, 48>(xp, xo, lds, tid);
    else                conv_pass<320, 5, 640, 80, 40>(xp, xo, lds, tid);
    return;
  }
  int e = (bid - 3072) * 256 + tid;
  if (e >= 258048) return;
  int b = e >> 9, idx = e & 511;
  int lane = idx >> 3, eo = idx & 7;
  int mat = b / 168, r = b - mat * 168;
  int li, n, MUL, c2, ks;
  if (r < 128) {
    li = 0; MUL = 256;
    int h = r >> 4, t = r & 15;
    int nt = t >> 3; c2 = (t >> 2) & 1; ks = t & 3;
    n = h * 32 + nt * 16 + (lane & 15);
  } else if (r < 160) {
    li = 1; MUL = 128;
    int r2 = r - 128; int h = r2 >> 2, t = r2 & 3;
    c2 = t >> 1; ks = t & 1;
    n = h * 16 + (lane & 15);
  } else {
    li = 2; MUL = 64;
    int r2 = r - 160; int hp = r2 >> 1;
    c2 = r2 & 1; ks = 0;
    n = hp * 16 + (lane & 15);
  }
  int m = c2 * (MUL >> 1) + ks * 32 + (lane >> 4) * 8 + eo;
  const float* src;
  if (mat == 0)      src = (li == 0) ? q0 : (li == 1) ? q1 : q2;
  else if (mat == 1) src = (li == 0) ? k0 : (li == 1) ? k1 : k2;
  else               src = (li == 0) ? v0 : (li == 1) ? v1 : v2;
  float scale = (li == 0) ? 0.0625f : (li == 1) ? 0.08838834764831845f : 0.125f;
  if (mat == 0) {
    float qext = (li == 0) ? 1.0f : (li == 1) ? 0.5773502691896258f : 0.4472135954999579f;
    scale *= ATTN_NORM * LOG2E * qext;
  }
  ws[e] = f2bf(src[m * MUL + n] * scale);
}

// ============ per-l QKV: all x-frags hoisted within phase + setprio'd MFMA stream ============
template<int L>
__device__ __forceinline__ void qkv_l(const unsigned short* __restrict__ xwb,
                                      const unsigned short* __restrict__ ws,
                                      char* __restrict__ sQ, char* __restrict__ sK,
                                      char* __restrict__ sVT,
                                      int h, int lane, int wvi) {
  constexpr int D    = (L == 0) ? 1 : (L == 1) ? 3 : 5;
  constexpr int NPL  = (L == 0) ? 32 : (L == 1) ? 16 : 8;
  constexpr int NT   = (L == 0) ? 2 : 1;
  constexpr int KS   = (L == 0) ? 4 : (L == 1) ? 2 : 1;
  constexpr int COFF = (L == 0) ? 0 : (L == 1) ? 32 : 80;
  constexpr int XB   = (L == 0) ? 0 : (L == 1) ? 32 : 80;
  constexpr int XC2  = KS * 4 * D;
  constexpr int NG   = 2 * KS;
  const int l15 = lane & 15, blk = lane >> 4;

  short8v xf[NG][D];
  #pragma unroll
  for (int g = 0; g < NG; ++g) {
    const int c2 = g / KS, ks = g - c2 * KS;
    #pragma unroll
    for (int j = 0; j < D; ++j)
      xf[g][j] = *(const short8v*)(xwb + (XB + c2 * XC2 + ks * 4 * D + j * 4 + wvi) * 512 + lane * 8);
  }

  f32x4 acc[3][NT][D];
  #pragma unroll
  for (int a = 0; a < 3; ++a)
    #pragma unroll
    for (int nt = 0; nt < NT; ++nt)
      #pragma unroll
      for (int j = 0; j < D; ++j)
        acc[a][nt][j] = (f32x4){0.f, 0.f, 0.f, 0.f};

  // T5: prioritize this wave's W-load + MFMA stream over co-resident WGs'
  // VALU phases (3 WGs/CU at different phases -> scheduler has real choice).
  __builtin_amdgcn_s_setprio(1);
  #pragma unroll
  for (int g = 0; g < NG; ++g) {
    const int c2 = g / KS, ks = g - c2 * KS;
    #pragma unroll
    for (int mat = 0; mat < 3; ++mat) {
      #pragma unroll
      for (int nt = 0; nt < NT; ++nt) {
        int wb;
        if constexpr (L == 0)      wb = mat * 168 + h * 16 + nt * 8 + c2 * 4 + ks;
        else if constexpr (L == 1) wb = mat * 168 + 128 + h * 4 + c2 * 2 + ks;
        else                       wb = mat * 168 + 160 + (h >> 1) * 2 + c2;
        short8v wf = *(const short8v*)(ws + wb * 512 + lane * 8);
        #pragma unroll
        for (int j = 0; j < D; ++j)
          acc[mat][nt][j] = __builtin_amdgcn_mfma_f32_16x16x32_bf16(wf, xf[g][j], acc[mat][nt][j], 0, 0, 0);
      }
    }
  }
  __builtin_amdgcn_s_setprio(0);

  const int q = wvi * 16 + l15;
  const int qsw = (q & 7) << 4;
  #pragma unroll
  for (int nt = 0; nt < NT; ++nt) {
    #pragma unroll
    for (int j = 0; j < D; ++j) {
      int cb; bool valid;
      if constexpr (L == 2) { valid = ((blk >> 1) == (h & 1)); cb = COFF + j * NPL + (blk & 1) * 4; }
      else                  { valid = true;                    cb = COFF + j * NPL + nt * 16 + blk * 4; }
      if (valid) {
        uint32_t q01 = pack2bf(acc[0][nt][j][0], acc[0][nt][j][1]);
        uint32_t q23 = pack2bf(acc[0][nt][j][2], acc[0][nt][j][3]);
        uint32_t k01 = pack2bf(acc[1][nt][j][0], acc[1][nt][j][1]);
        uint32_t k23 = pack2bf(acc[1][nt][j][2], acc[1][nt][j][3]);
        int sw = (cb * 2) ^ qsw;
        *(uint2*)(sQ + q * 256 + sw) = make_uint2(q01, q23);
        *(uint2*)(sK + q * 256 + sw) = make_uint2(k01, k23);
        #pragma unroll
        for (int reg = 0; reg < 4; ++reg) {
          int c = cb + reg;
          *(unsigned short*)(sVT + c * 128 + ((q * 2) ^ ((c & 7) << 4))) = f2bf_fast(acc[2][nt][j][reg]);
        }
      }
    }
  }
}

// ============ main attention kernel (R14/R18 proven best + QKV setprio) ============
__launch_bounds__(256, 3)
__global__ void orbattn19(const float* __restrict__ x,
                          const unsigned short* __restrict__ ws,
                          const unsigned short* __restrict__ xw,
                          float* __restrict__ out) {
  extern __shared__ char smem[];
  char* sQ  = smem;           // [64][128] bf16 = 16384
  char* sK  = smem + 16384;   // 16384
  char* sVT = smem + 32768;   // [128][64] bf16 = 16384   total 49152
  char* sP  = smem;           // overlaps sQ (after bar2)
  int tid = threadIdx.x;
  int bid = blockIdx.x;
  // XCD-grouped: all 8 heads of a batch on one XCD (xw[b] L2 reuse)
  int xcd = bid & 7, t = bid >> 3;
  int h = t & 7;
  int b = (t >> 3) * 8 + xcd;
  const float* xb = x + (size_t)b * 61440;
  float* ob = out + (size_t)b * 61440;
  const unsigned short* xwb = xw + (size_t)b * 61440;
  const int lane = tid & 63, wvi = tid >> 6, l15 = lane & 15, blk = lane >> 4;

  // zero pad ch 120..127 of Q,K and rows 120..127 of V^T
  for (int f = tid; f < 512; f += 256) {
    int q = f >> 3, c = 120 + (f & 7);
    int sw = (c * 2) ^ ((q & 7) << 4);
    *(unsigned short*)(sQ + q * 256 + sw) = 0;
    *(unsigned short*)(sK + q * 256 + sw) = 0;
    *(unsigned short*)(sVT + c * 128 + ((q * 2) ^ ((c & 7) << 4))) = 0;
  }

  qkv_l<0>(xwb, ws, sQ, sK, sVT, h, lane, wvi);
  qkv_l<1>(xwb, ws, sQ, sK, sVT, h, lane, wvi);
  qkv_l<2>(xwb, ws, sQ, sK, sVT, h, lane, wvi);
  __syncthreads();   // bar1: Q,K,V in LDS

  // ---- logits, SWAPPED operands: lacc[kt] holds S[k=kt*16+blk*4+reg][q=wvi*16+l15]
  f32x4 lacc[4];
  #pragma unroll
  for (int kt = 0; kt < 4; ++kt) lacc[kt] = (f32x4){0.f, 0.f, 0.f, 0.f};
  __builtin_amdgcn_s_setprio(1);
  #pragma unroll
  for (int ks = 0; ks < 4; ++ks) {
    int qr = wvi * 16 + l15;
    int bc = (ks * 32 + blk * 8) * 2;
    short8v qf = *(const short8v*)(sQ + qr * 256 + (bc ^ ((qr & 7) << 4)));
    #pragma unroll
    for (int kt = 0; kt < 4; ++kt) {
      int kr = kt * 16 + l15;
      short8v kf = *(const short8v*)(sK + kr * 256 + (bc ^ ((kr & 7) << 4)));
      lacc[kt] = __builtin_amdgcn_mfma_f32_16x16x32_bf16(kf, qf, lacc[kt], 0, 0, 0);
    }
  }
  __builtin_amdgcn_s_setprio(0);
  // ---- softmax over k: each lane owns q=wvi*16+l15 with 16 k-values in-lane;
  //      cross-lane reduce only over blk groups -> 2 shfls
  float mx = lacc[0][0];
  #pragma unroll
  for (int kt = 0; kt < 4; ++kt)
    #pragma unroll
    for (int reg = 0; reg < 4; ++reg) mx = fmaxf(mx, lacc[kt][reg]);
  mx = fmaxf(mx, __shfl_xor(mx, 16, 64));
  mx = fmaxf(mx, __shfl_xor(mx, 32, 64));
  float p[4][4], s = 0.f;
  #pragma unroll
  for (int kt = 0; kt < 4; ++kt)
    #pragma unroll
    for (int reg = 0; reg < 4; ++reg) { p[kt][reg] = exp2f(lacc[kt][reg] - mx); s += p[kt][reg]; }
  s += __shfl_xor(s, 16, 64);
  s += __shfl_xor(s, 32, 64);
  float inv = 1.0f / s;
  __syncthreads();   // bar2: all sQ reads done; safe to overwrite with P

  // ---- packed P write: lane holds 4 consecutive k per kt -> ds_write_b64
  {
    int q = wvi * 16 + l15;
    int qsw = (q & 7) << 4;
    #pragma unroll
    for (int kt = 0; kt < 4; ++kt) {
      uint32_t u0 = pack2bf(p[kt][0] * inv, p[kt][1] * inv);
      uint32_t u1 = pack2bf(p[kt][2] * inv, p[kt][3] * inv);
      int k0b = (kt * 16 + blk * 4) * 2;
      *(uint2*)(sP + q * 128 + (k0b ^ qsw)) = make_uint2(u0, u1);
    }
  }
  __syncthreads();   // bar3: REQUIRED — P read is cross-lane (lane reads other
                     // lanes' writes); without a barrier the DRF LDS model lets
                     // the compiler reorder (per-lane addresses are disjoint).

  // ---- hoisted residual loads: issue before PV so MFMA hides their latency
  float xv[8][4];
  #pragma unroll
  for (int ct = 0; ct < 8; ++ct) {
    int c = ct * 16 + l15;
    if (c < 120) {
      int o;
      if (c < 32) o = h * 32 + c;
      else if (c < 80) { int cc = c - 32; int i = cc >> 4, nl = cc & 15; o = 256 + (h * 16 + nl) * 3 + i; }
      else             { int cc = c - 80; int i = cc >> 3, nl = cc & 7;  o = 640 + (h * 8 + nl) * 5 + i; }
      #pragma unroll
      for (int reg = 0; reg < 4; ++reg) {
        int q = wvi * 16 + blk * 4 + reg;
        xv[ct][reg] = xb[q * 960 + o];
      }
    }
  }

  // ---- PV: U[q][c] = sum_k P[q][k] V_T[c][k]
  f32x4 uacc[8];
  #pragma unroll
  for (int ct = 0; ct < 8; ++ct) uacc[ct] = (f32x4){0.f, 0.f, 0.f, 0.f};
  __builtin_amdgcn_s_setprio(1);
  #pragma unroll
  for (int ks = 0; ks < 2; ++ks) {
    int qr = wvi * 16 + l15;
    int bc = (ks * 32 + blk * 8) * 2;
    short8v pf = *(const short8v*)(sP + qr * 128 + (bc ^ ((qr & 7) << 4)));
    #pragma unroll
    for (int ct = 0; ct < 8; ++ct) {
      int cr = ct * 16 + l15;
      short8v vf = *(const short8v*)(sVT + cr * 128 + (bc ^ ((cr & 7) << 4)));
      uacc[ct] = __builtin_amdgcn_mfma_f32_16x16x32_bf16(pf, vf, uacc[ct], 0, 0, 0);
    }
  }
  __builtin_amdgcn_s_setprio(0);
  // ---- epilogue: out = x + update (i-major channel map), residual already in regs
  #pragma unroll
  for (int ct = 0; ct < 8; ++ct) {
    int c = ct * 16 + l15;
    if (c < 120) {
      int o;
      if (c < 32) o = h * 32 + c;
      else if (c < 80) { int cc = c - 32; int i = cc >> 4, nl = cc & 15; o = 256 + (h * 16 + nl) * 3 + i; }
      else             { int cc = c - 80; int i = cc >> 3, nl = cc & 7;  o = 640 + (h * 8 + nl) * 5 + i; }
      #pragma unroll
      for (int reg = 0; reg < 4; ++reg) {
        int q = wvi * 16 + blk * 4 + reg;
        ob[q * 960 + o] = xv[ct][reg] + uacc[ct][reg];
      }
    }
  }
}

extern "C" void kernel_launch(void* const* d_in, const int* in_sizes, int n_in,
                              void* d_out, int out_size, void* d_ws, size_t ws_size,
                              hipStream_t stream) {
  const float* x = (const float*)d_in[0];
  unsigned short* wsw = (unsigned short*)d_ws;                        // 516096 B
  unsigned short* xw = (unsigned short*)((char*)d_ws + 516096);      // ~126 MB
  float* out = (float*)d_out;
  prep_conv<<<4080, 256, 0, stream>>>(
      x,
      (const float*)d_in[1], (const float*)d_in[2], (const float*)d_in[3],
      (const float*)d_in[4], (const float*)d_in[5], (const float*)d_in[6],
      (const float*)d_in[7], (const float*)d_in[8], (const float*)d_in[9],
      wsw, xw);
  hipFuncSetAttribute((const void*)orbattn19, hipFuncAttributeMaxDynamicSharedMemorySize, 49152);
  orbattn19<<<8192, 256, 49152, stream>>>(x, wsw, xw, out);
}

// Round 20
// 307.191 us; speedup vs baseline: 1.1482x; 1.1482x over previous
//
#include <hip/hip_runtime.h>
#include <stdint.h>

typedef __attribute__((ext_vector_type(8))) short short8v;
typedef __attribute__((ext_vector_type(4))) float f32x4;

#define ATTN_NORM 0.13363062095621219f
#define LOG2E 1.4426950408889634f

// exact RNE (used only in W-prep, off the hot path)
__device__ __forceinline__ unsigned short f2bf(float f) {
  union { float f; uint32_t u; } v; v.f = f;
  uint32_t u = v.u;
  u += 0x7fffu + ((u >> 16) & 1u);
  return (unsigned short)(u >> 16);
}

// fast round-half-up scalar (2 VALU)
__device__ __forceinline__ unsigned short f2bf_fast(float f) {
  union { float f; uint32_t u; } v; v.f = f;
  return (unsigned short)((v.u + 0x8000u) >> 16);
}

// fast packed pair: 2 adds + 1 v_perm_b32 (builtin — asm cvt_pk is banned: R3/R8/R9 NaN)
__device__ __forceinline__ uint32_t pack2bf(float lo, float hi) {
  union { float f; uint32_t u; } a, b;
  a.f = lo; b.f = hi;
  return __builtin_amdgcn_perm(b.u + 0x8000u, a.u + 0x8000u, 0x07060302u);
}

// ============ fused prep(W) + conv(x) kernel (proven R14) ============
template<int W, int D, int XO, int BLK0, int NB>
__device__ __forceinline__ void conv_pass(const float* __restrict__ xp,
                                          unsigned short* __restrict__ xo,
                                          unsigned short* __restrict__ lds, int tid) {
  constexpr int PITCH = W + 8;
  #pragma unroll 2
  for (int f = tid; f < 64 * (W / 4); f += 256) {
    int tok = f / (W / 4);
    int c4 = f - tok * (W / 4);
    float4 v = *(const float4*)(xp + tok * 960 + XO + c4 * 4);
    uint2 pk = make_uint2(pack2bf(v.x, v.y), pack2bf(v.z, v.w));
    *(uint2*)(lds + tok * PITCH + c4 * 4) = pk;
  }
  __syncthreads();
  #pragma unroll 2
  for (int f = tid; f < NB * 64; f += 256) {
    int bl = f >> 6, lane = f & 63;
    int mb, i, qt;
    if (D == 1) {
      int c2 = bl >> 4, t = bl & 15;
      mb = c2 * 128 + (t >> 2) * 32; i = 0; qt = t & 3;
    } else if (D == 3) {
      int c2 = bl / 24; int t = bl - c2 * 24;
      int ks = t / 12; int rt = t - ks * 12;
      mb = c2 * 64 + ks * 32; i = rt >> 2; qt = rt & 3;
    } else {
      int c2 = bl / 20; int rt = bl - c2 * 20;
      mb = c2 * 32; i = rt >> 2; qt = rt & 3;
    }
    int tok = qt * 16 + (lane & 15);
    int m0 = mb + (lane >> 4) * 8;
    const unsigned short* base = lds + tok * PITCH + m0 * D + i;
    union { unsigned short o[8]; short8v s; } pk;
    #pragma unroll
    for (int e = 0; e < 8; ++e) pk.o[e] = base[e * D];
    *(short8v*)(xo + (BLK0 + bl) * 512 + lane * 8) = pk.s;
  }
}

__launch_bounds__(256)
__global__ void prep_conv(const float* __restrict__ x,
                          const float* q0, const float* q1, const float* q2,
                          const float* k0, const float* k1, const float* k2,
                          const float* v0, const float* v1, const float* v2,
                          unsigned short* __restrict__ ws,
                          unsigned short* __restrict__ xw) {
  __shared__ unsigned short lds[25088];
  int bid = blockIdx.x, tid = threadIdx.x;
  if (bid < 3072) {
    int b, pass;
    if (bid < 1024)       { b = bid;        pass = 0; }
    else if (bid < 2048)  { b = bid - 1024; pass = 1; }
    else                  { b = bid - 2048; pass = 2; }
    const float* xp = x + (size_t)b * 61440;
    unsigned short* xo = xw + (size_t)b * 61440;
    if (pass == 0)      conv_pass<256, 1,   0,  0, 32>(xp, xo, lds, tid);
    else if (pass == 1) conv_pass<384, 3, 256, 32, 48>(xp, xo, lds, tid);
    else                conv_pass<320, 5, 640, 80, 40>(xp, xo, lds, tid);
    return;
  }
  int e = (bid - 3072) * 256 + tid;
  if (e >= 258048) return;
  int b = e >> 9, idx = e & 511;
  int lane = idx >> 3, eo = idx & 7;
  int mat = b / 168, r = b - mat * 168;
  int li, n, MUL, c2, ks;
  if (r < 128) {
    li = 0; MUL = 256;
    int h = r >> 4, t = r & 15;
    int nt = t >> 3; c2 = (t >> 2) & 1; ks = t & 3;
    n = h * 32 + nt * 16 + (lane & 15);
  } else if (r < 160) {
    li = 1; MUL = 128;
    int r2 = r - 128; int h = r2 >> 2, t = r2 & 3;
    c2 = t >> 1; ks = t & 1;
    n = h * 16 + (lane & 15);
  } else {
    li = 2; MUL = 64;
    int r2 = r - 160; int hp = r2 >> 1;
    c2 = r2 & 1; ks = 0;
    n = hp * 16 + (lane & 15);
  }
  int m = c2 * (MUL >> 1) + ks * 32 + (lane >> 4) * 8 + eo;
  const float* src;
  if (mat == 0)      src = (li == 0) ? q0 : (li == 1) ? q1 : q2;
  else if (mat == 1) src = (li == 0) ? k0 : (li == 1) ? k1 : k2;
  else               src = (li == 0) ? v0 : (li == 1) ? v1 : v2;
  float scale = (li == 0) ? 0.0625f : (li == 1) ? 0.08838834764831845f : 0.125f;
  if (mat == 0) {
    float qext = (li == 0) ? 1.0f : (li == 1) ? 0.5773502691896258f : 0.4472135954999579f;
    scale *= ATTN_NORM * LOG2E * qext;
  }
  ws[e] = f2bf(src[m * MUL + n] * scale);
}

// ============ per-l QKV: all x-frags hoisted within phase (R6/R10 proven) ============
template<int L>
__device__ __forceinline__ void qkv_l(const unsigned short* __restrict__ xwb,
                                      const unsigned short* __restrict__ ws,
                                      char* __restrict__ sQ, char* __restrict__ sK,
                                      char* __restrict__ sVT,
                                      int h, int lane, int wvi) {
  constexpr int D    = (L == 0) ? 1 : (L == 1) ? 3 : 5;
  constexpr int NPL  = (L == 0) ? 32 : (L == 1) ? 16 : 8;
  constexpr int NT   = (L == 0) ? 2 : 1;
  constexpr int KS   = (L == 0) ? 4 : (L == 1) ? 2 : 1;
  constexpr int COFF = (L == 0) ? 0 : (L == 1) ? 32 : 80;
  constexpr int XB   = (L == 0) ? 0 : (L == 1) ? 32 : 80;
  constexpr int XC2  = KS * 4 * D;
  constexpr int NG   = 2 * KS;
  const int l15 = lane & 15, blk = lane >> 4;

  short8v xf[NG][D];
  #pragma unroll
  for (int g = 0; g < NG; ++g) {
    const int c2 = g / KS, ks = g - c2 * KS;
    #pragma unroll
    for (int j = 0; j < D; ++j)
      xf[g][j] = *(const short8v*)(xwb + (XB + c2 * XC2 + ks * 4 * D + j * 4 + wvi) * 512 + lane * 8);
  }

  f32x4 acc[3][NT][D];
  #pragma unroll
  for (int a = 0; a < 3; ++a)
    #pragma unroll
    for (int nt = 0; nt < NT; ++nt)
      #pragma unroll
      for (int j = 0; j < D; ++j)
        acc[a][nt][j] = (f32x4){0.f, 0.f, 0.f, 0.f};

  #pragma unroll
  for (int g = 0; g < NG; ++g) {
    const int c2 = g / KS, ks = g - c2 * KS;
    #pragma unroll
    for (int mat = 0; mat < 3; ++mat) {
      #pragma unroll
      for (int nt = 0; nt < NT; ++nt) {
        int wb;
        if constexpr (L == 0)      wb = mat * 168 + h * 16 + nt * 8 + c2 * 4 + ks;
        else if constexpr (L == 1) wb = mat * 168 + 128 + h * 4 + c2 * 2 + ks;
        else                       wb = mat * 168 + 160 + (h >> 1) * 2 + c2;
        short8v wf = *(const short8v*)(ws + wb * 512 + lane * 8);
        #pragma unroll
        for (int j = 0; j < D; ++j)
          acc[mat][nt][j] = __builtin_amdgcn_mfma_f32_16x16x32_bf16(wf, xf[g][j], acc[mat][nt][j], 0, 0, 0);
      }
    }
  }

  const int q = wvi * 16 + l15;
  const int qsw = (q & 7) << 4;
  #pragma unroll
  for (int nt = 0; nt < NT; ++nt) {
    #pragma unroll
    for (int j = 0; j < D; ++j) {
      int cb; bool valid;
      if constexpr (L == 2) { valid = ((blk >> 1) == (h & 1)); cb = COFF + j * NPL + (blk & 1) * 4; }
      else                  { valid = true;                    cb = COFF + j * NPL + nt * 16 + blk * 4; }
      if (valid) {
        uint32_t q01 = pack2bf(acc[0][nt][j][0], acc[0][nt][j][1]);
        uint32_t q23 = pack2bf(acc[0][nt][j][2], acc[0][nt][j][3]);
        uint32_t k01 = pack2bf(acc[1][nt][j][0], acc[1][nt][j][1]);
        uint32_t k23 = pack2bf(acc[1][nt][j][2], acc[1][nt][j][3]);
        int sw = (cb * 2) ^ qsw;
        *(uint2*)(sQ + q * 256 + sw) = make_uint2(q01, q23);
        *(uint2*)(sK + q * 256 + sw) = make_uint2(k01, k23);
        #pragma unroll
        for (int reg = 0; reg < 4; ++reg) {
          int c = cb + reg;
          *(unsigned short*)(sVT + c * 128 + ((q * 2) ^ ((c & 7) << 4))) = f2bf_fast(acc[2][nt][j][reg]);
        }
      }
    }
  }
}

// ============ main attention kernel (R14/R18 proven best — final) ============
__launch_bounds__(256, 3)
__global__ void orbattn20(const float* __restrict__ x,
                          const unsigned short* __restrict__ ws,
                          const unsigned short* __restrict__ xw,
                          float* __restrict__ out) {
  extern __shared__ char smem[];
  char* sQ  = smem;           // [64][128] bf16 = 16384
  char* sK  = smem + 16384;   // 16384
  char* sVT = smem + 32768;   // [128][64] bf16 = 16384   total 49152
  char* sP  = smem;           // overlaps sQ (after bar2)
  int tid = threadIdx.x;
  int bid = blockIdx.x;
  // XCD-grouped: all 8 heads of a batch on one XCD (xw[b] L2 reuse)
  int xcd = bid & 7, t = bid >> 3;
  int h = t & 7;
  int b = (t >> 3) * 8 + xcd;
  const float* xb = x + (size_t)b * 61440;
  float* ob = out + (size_t)b * 61440;
  const unsigned short* xwb = xw + (size_t)b * 61440;
  const int lane = tid & 63, wvi = tid >> 6, l15 = lane & 15, blk = lane >> 4;

  // zero pad ch 120..127 of Q,K and rows 120..127 of V^T
  for (int f = tid; f < 512; f += 256) {
    int q = f >> 3, c = 120 + (f & 7);
    int sw = (c * 2) ^ ((q & 7) << 4);
    *(unsigned short*)(sQ + q * 256 + sw) = 0;
    *(unsigned short*)(sK + q * 256 + sw) = 0;
    *(unsigned short*)(sVT + c * 128 + ((q * 2) ^ ((c & 7) << 4))) = 0;
  }

  qkv_l<0>(xwb, ws, sQ, sK, sVT, h, lane, wvi);
  qkv_l<1>(xwb, ws, sQ, sK, sVT, h, lane, wvi);
  qkv_l<2>(xwb, ws, sQ, sK, sVT, h, lane, wvi);
  __syncthreads();   // bar1: Q,K,V in LDS

  // ---- logits, SWAPPED operands: lacc[kt] holds S[k=kt*16+blk*4+reg][q=wvi*16+l15]
  f32x4 lacc[4];
  #pragma unroll
  for (int kt = 0; kt < 4; ++kt) lacc[kt] = (f32x4){0.f, 0.f, 0.f, 0.f};
  __builtin_amdgcn_s_setprio(1);
  #pragma unroll
  for (int ks = 0; ks < 4; ++ks) {
    int qr = wvi * 16 + l15;
    int bc = (ks * 32 + blk * 8) * 2;
    short8v qf = *(const short8v*)(sQ + qr * 256 + (bc ^ ((qr & 7) << 4)));
    #pragma unroll
    for (int kt = 0; kt < 4; ++kt) {
      int kr = kt * 16 + l15;
      short8v kf = *(const short8v*)(sK + kr * 256 + (bc ^ ((kr & 7) << 4)));
      lacc[kt] = __builtin_amdgcn_mfma_f32_16x16x32_bf16(kf, qf, lacc[kt], 0, 0, 0);
    }
  }
  __builtin_amdgcn_s_setprio(0);
  // ---- softmax over k: each lane owns q=wvi*16+l15 with 16 k-values in-lane;
  //      cross-lane reduce only over blk groups -> 2 shfls (was 32)
  float mx = lacc[0][0];
  #pragma unroll
  for (int kt = 0; kt < 4; ++kt)
    #pragma unroll
    for (int reg = 0; reg < 4; ++reg) mx = fmaxf(mx, lacc[kt][reg]);
  mx = fmaxf(mx, __shfl_xor(mx, 16, 64));
  mx = fmaxf(mx, __shfl_xor(mx, 32, 64));
  float p[4][4], s = 0.f;
  #pragma unroll
  for (int kt = 0; kt < 4; ++kt)
    #pragma unroll
    for (int reg = 0; reg < 4; ++reg) { p[kt][reg] = exp2f(lacc[kt][reg] - mx); s += p[kt][reg]; }
  s += __shfl_xor(s, 16, 64);
  s += __shfl_xor(s, 32, 64);
  float inv = 1.0f / s;
  __syncthreads();   // bar2: all sQ reads done; safe to overwrite with P

  // ---- packed P write: lane holds 4 consecutive k per kt -> ds_write_b64
  {
    int q = wvi * 16 + l15;
    int qsw = (q & 7) << 4;
    #pragma unroll
    for (int kt = 0; kt < 4; ++kt) {
      uint32_t u0 = pack2bf(p[kt][0] * inv, p[kt][1] * inv);
      uint32_t u1 = pack2bf(p[kt][2] * inv, p[kt][3] * inv);
      int k0b = (kt * 16 + blk * 4) * 2;
      *(uint2*)(sP + q * 128 + (k0b ^ qsw)) = make_uint2(u0, u1);
    }
  }
  __syncthreads();   // bar3: REQUIRED — P read is cross-lane; DRF LDS model
                     // allows reorder without it (R3/R8 lesson).

  // ---- hoisted residual loads: issue before PV so MFMA hides their latency
  float xv[8][4];
  #pragma unroll
  for (int ct = 0; ct < 8; ++ct) {
    int c = ct * 16 + l15;
    if (c < 120) {
      int o;
      if (c < 32) o = h * 32 + c;
      else if (c < 80) { int cc = c - 32; int i = cc >> 4, nl = cc & 15; o = 256 + (h * 16 + nl) * 3 + i; }
      else             { int cc = c - 80; int i = cc >> 3, nl = cc & 7;  o = 640 + (h * 8 + nl) * 5 + i; }
      #pragma unroll
      for (int reg = 0; reg < 4; ++reg) {
        int q = wvi * 16 + blk * 4 + reg;
        xv[ct][reg] = xb[q * 960 + o];
      }
    }
  }

  // ---- PV: U[q][c] = sum_k P[q][k] V_T[c][k]
  f32x4 uacc[8];
  #pragma unroll
  for (int ct = 0; ct < 8; ++ct) uacc[ct] = (f32x4){0.f, 0.f, 0.f, 0.f};
  __builtin_amdgcn_s_setprio(1);
  #pragma unroll
  for (int ks = 0; ks < 2; ++ks) {
    int qr = wvi * 16 + l15;
    int bc = (ks * 32 + blk * 8) * 2;
    short8v pf = *(const short8v*)(sP + qr * 128 + (bc ^ ((qr & 7) << 4)));
    #pragma unroll
    for (int ct = 0; ct < 8; ++ct) {
      int cr = ct * 16 + l15;
      short8v vf = *(const short8v*)(sVT + cr * 128 + (bc ^ ((cr & 7) << 4)));
      uacc[ct] = __builtin_amdgcn_mfma_f32_16x16x32_bf16(pf, vf, uacc[ct], 0, 0, 0);
    }
  }
  __builtin_amdgcn_s_setprio(0);
  // ---- epilogue: out = x + update (i-major channel map), residual already in regs
  #pragma unroll
  for (int ct = 0; ct < 8; ++ct) {
    int c = ct * 16 + l15;
    if (c < 120) {
      int o;
      if (c < 32) o = h * 32 + c;
      else if (c < 80) { int cc = c - 32; int i = cc >> 4, nl = cc & 15; o = 256 + (h * 16 + nl) * 3 + i; }
      else             { int cc = c - 80; int i = cc >> 3, nl = cc & 7;  o = 640 + (h * 8 + nl) * 5 + i; }
      #pragma unroll
      for (int reg = 0; reg < 4; ++reg) {
        int q = wvi * 16 + blk * 4 + reg;
        ob[q * 960 + o] = xv[ct][reg] + uacc[ct][reg];
      }
    }
  }
}

extern "C" void kernel_launch(void* const* d_in, const int* in_sizes, int n_in,
                              void* d_out, int out_size, void* d_ws, size_t ws_size,
                              hipStream_t stream) {
  const float* x = (const float*)d_in[0];
  unsigned short* wsw = (unsigned short*)d_ws;                        // 516096 B
  unsigned short* xw = (unsigned short*)((char*)d_ws + 516096);      // ~126 MB
  float* out = (float*)d_out;
  prep_conv<<<4080, 256, 0, stream>>>(
      x,
      (const float*)d_in[1], (const float*)d_in[2], (const float*)d_in[3],
      (const float*)d_in[4], (const float*)d_in[5], (const float*)d_in[6],
      (const float*)d_in[7], (const float*)d_in[8], (const float*)d_in[9],
      wsw, xw);
  hipFuncSetAttribute((const void*)orbattn20, hipFuncAttributeMaxDynamicSharedMemorySize, 49152);
  orbattn20<<<8192, 256, 49152, stream>>>(x, wsw, xw, out);
}